// Round 1
// baseline (333.420 us; speedup 1.0000x reference)
//
#include <hip/hip_runtime.h>
#include <math.h>

// ---------------------------------------------------------------------------
// Encoder_Flows: 4x (out = agg@w_l^T + b_l + x@w_r^T; x = out/||out||) ; relu
// agg only affects rows [0,1024) of the 32768-row flattened x (reference
// slices x[:k] of the FLATTENED array). agg@w_l^T == prefix_sum(x@w_l^T)/cnt.
// ---------------------------------------------------------------------------

constexpr int BM = 32;
constexpr int BK = 32;
constexpr int NROWS = 32768;   // 32 * 1024
constexpr int KROWS = 1024;    // rows that receive the agg term
constexpr int KSPLIT = 4;

// MODE: 0 = proj (store raw partial GEMM result, used for Y = x_k @ w_l^T)
//       1 = main (add bias + agg(if row<1024), L2-normalize row)
//       2 = main + relu (final layer)
template<int DOUT, int MODE>
__global__ __launch_bounds__(256)
void gemm_kernel(const float* __restrict__ X,
                 const float* __restrict__ W,     // (DOUT, din) row-major
                 const float* __restrict__ bias,  // (DOUT)
                 const float* __restrict__ aggp,  // (1024, DOUT)
                 float* __restrict__ out,
                 int din, int kchunk)
{
    constexpr int C = DOUT / 32;             // cols per thread
    __shared__ float As[BK][BM + 4];         // +4 pad: aligned float4 rows
    __shared__ float Bs[BK][DOUT + 4];

    const int t  = threadIdx.x;              // 256 threads
    const int tx = t & 31;                   // col lane
    const int ty = t >> 5;                   // row group 0..7
    const int i0 = blockIdx.x * BM;          // row-block origin
    const int k0 = blockIdx.y * kchunk;      // k-split origin (proj only)
    const int k1 = k0 + kchunk;
    // proj partials land at consecutive 1024xDOUT slabs
    float* outp = out + (size_t)blockIdx.y * KROWS * DOUT;

    float acc[4][C];
#pragma unroll
    for (int r = 0; r < 4; ++r)
#pragma unroll
        for (int c = 0; c < C; ++c) acc[r][c] = 0.f;

    const int ml = t >> 3;                   // A-tile row this thread loads
    const int kq = (t & 7) * 4;              // A/B-tile k quad

    for (int k = k0; k < k1; k += BK) {
        __syncthreads();
        // --- stage A tile (BM x BK), coalesced float4 along k ---
        float4 a4 = *reinterpret_cast<const float4*>(
            &X[(size_t)(i0 + ml) * din + k + kq]);
        As[kq + 0][ml] = a4.x; As[kq + 1][ml] = a4.y;
        As[kq + 2][ml] = a4.z; As[kq + 3][ml] = a4.w;
        // --- stage B tile (BK x DOUT), transposed into LDS ---
#pragma unroll
        for (int cc = 0; cc < C; ++cc) {
            const int o = (t >> 3) + 32 * cc;
            float4 w4 = *reinterpret_cast<const float4*>(
                &W[(size_t)o * din + k + kq]);
            Bs[kq + 0][o] = w4.x; Bs[kq + 1][o] = w4.y;
            Bs[kq + 2][o] = w4.z; Bs[kq + 3][o] = w4.w;
        }
        __syncthreads();
#pragma unroll
        for (int kk = 0; kk < BK; ++kk) {
            float4 av = *reinterpret_cast<const float4*>(&As[kk][ty * 4]);
            float a_[4] = {av.x, av.y, av.z, av.w};
#pragma unroll
            for (int c = 0; c < C; ++c) {
                float b = Bs[kk][tx + 32 * c];
#pragma unroll
                for (int r = 0; r < 4; ++r)
                    acc[r][c] = fmaf(a_[r], b, acc[r][c]);
            }
        }
    }

    if (MODE == 0) {
#pragma unroll
        for (int r = 0; r < 4; ++r) {
            const int i = i0 + ty * 4 + r;
#pragma unroll
            for (int c = 0; c < C; ++c)
                outp[(size_t)i * DOUT + tx + 32 * c] = acc[r][c];
        }
    } else {
        float bb[C];
#pragma unroll
        for (int c = 0; c < C; ++c) bb[c] = bias[tx + 32 * c];
        const bool has_agg = (i0 < KROWS);
#pragma unroll
        for (int r = 0; r < 4; ++r) {
            const int i = i0 + ty * 4 + r;
            float ss = 0.f;
#pragma unroll
            for (int c = 0; c < C; ++c) {
                float v = acc[r][c] + bb[c];
                if (has_agg) v += aggp[(size_t)i * DOUT + tx + 32 * c];
                acc[r][c] = v;
                ss += v * v;
            }
            // reduce sum-of-squares across the 32 lanes holding this row
#pragma unroll
            for (int m = 16; m >= 1; m >>= 1) ss += __shfl_xor(ss, m, 32);
            const float inv = 1.0f / fmaxf(sqrtf(ss), 1e-12f);
#pragma unroll
            for (int c = 0; c < C; ++c) {
                float v = acc[r][c] * inv;
                if (MODE == 2) v = fmaxf(v, 0.f);
                outp[(size_t)i * DOUT + tx + 32 * c] = v;
            }
        }
    }
}

// Exclusive prefix-mean over 1024 rows, per column. One block per column.
// aggp[i][o] = (sum_{j<i} Y[j][o]) / max(i,1),  Y = sum of KSPLIT partials.
template<int DOUT>
__global__ __launch_bounds__(256)
void scan_kernel(const float* __restrict__ Ypart, float* __restrict__ aggp)
{
    const int o = blockIdx.x;
    const int t = threadIdx.x;          // 256 threads, 4 rows each
    float v[4];
#pragma unroll
    for (int j = 0; j < 4; ++j) {
        const int i = t * 4 + j;
        float s = 0.f;
#pragma unroll
        for (int sp = 0; sp < KSPLIT; ++sp)
            s += Ypart[(size_t)sp * KROWS * DOUT + (size_t)i * DOUT + o];
        v[j] = s;
    }
    float tot = v[0] + v[1] + v[2] + v[3];
    // inclusive scan of per-thread totals across the block
    const int lane = t & 63;
    const int wid  = t >> 6;
    float x = tot;
#pragma unroll
    for (int d = 1; d < 64; d <<= 1) {
        float y = __shfl_up(x, d, 64);
        if (lane >= d) x += y;
    }
    __shared__ float wsum[4];
    if (lane == 63) wsum[wid] = x;
    __syncthreads();
    float base = 0.f;
    for (int w = 0; w < wid; ++w) base += wsum[w];
    float run = base + x - tot;          // exclusive prefix for row 4t
#pragma unroll
    for (int j = 0; j < 4; ++j) {
        const int i = t * 4 + j;
        aggp[(size_t)i * DOUT + o] = run / fmaxf((float)i, 1.0f);
        run += v[j];
    }
}

__global__ void write_scalar(float* p) { p[0] = 1.0f; }

extern "C" void kernel_launch(void* const* d_in, const int* in_sizes, int n_in,
                              void* d_out, int out_size, void* d_ws, size_t ws_size,
                              hipStream_t stream)
{
    const float* flow = (const float*)d_in[0];
    const float* wl1 = (const float*)d_in[1];
    const float* bl1 = (const float*)d_in[2];
    const float* wr1 = (const float*)d_in[3];
    const float* wl2 = (const float*)d_in[4];
    const float* bl2 = (const float*)d_in[5];
    const float* wr2 = (const float*)d_in[6];
    const float* wl3 = (const float*)d_in[7];
    const float* bl3 = (const float*)d_in[8];
    const float* wr3 = (const float*)d_in[9];
    const float* wl4 = (const float*)d_in[10];
    const float* bl4 = (const float*)d_in[11];
    const float* wr4 = (const float*)d_in[12];
    float* out = (float*)d_out;

    float* ws   = (float*)d_ws;
    float* xA   = ws;                                  // 32768*128
    float* xB   = xA + (size_t)NROWS * 128;            // 32768*256
    float* Yp   = xB + (size_t)NROWS * 256;            // KSPLIT*1024*256
    float* aggp = Yp + (size_t)KSPLIT * KROWS * 256;   // 1024*256

    const dim3 projGrid(KROWS / BM, KSPLIT);
    const dim3 mainGrid(NROWS / BM, 1);

    // ---- Layer 1: din=1024, dout=128, X=flow -> xA ----
    gemm_kernel<128, 0><<<projGrid, 256, 0, stream>>>(flow, wl1, nullptr, nullptr, Yp, 1024, 1024 / KSPLIT);
    scan_kernel<128><<<128, 256, 0, stream>>>(Yp, aggp);
    gemm_kernel<128, 1><<<mainGrid, 256, 0, stream>>>(flow, wr1, bl1, aggp, xA, 1024, 1024);

    // ---- Layer 2: din=128, dout=256, xA -> xB ----
    gemm_kernel<256, 0><<<projGrid, 256, 0, stream>>>(xA, wl2, nullptr, nullptr, Yp, 128, 128 / KSPLIT);
    scan_kernel<256><<<256, 256, 0, stream>>>(Yp, aggp);
    gemm_kernel<256, 1><<<mainGrid, 256, 0, stream>>>(xA, wr2, bl2, aggp, xB, 128, 128);

    // ---- Layer 3: din=256, dout=128, xB -> xA ----
    gemm_kernel<128, 0><<<projGrid, 256, 0, stream>>>(xB, wl3, nullptr, nullptr, Yp, 256, 256 / KSPLIT);
    scan_kernel<128><<<128, 256, 0, stream>>>(Yp, aggp);
    gemm_kernel<128, 1><<<mainGrid, 256, 0, stream>>>(xB, wr3, bl3, aggp, xA, 256, 256);

    // ---- Layer 4: din=128, dout=256 + ReLU, xA -> out ----
    gemm_kernel<256, 0><<<projGrid, 256, 0, stream>>>(xA, wl4, nullptr, nullptr, Yp, 128, 128 / KSPLIT);
    scan_kernel<256><<<256, 256, 0, stream>>>(Yp, aggp);
    gemm_kernel<256, 2><<<mainGrid, 256, 0, stream>>>(xA, wr4, bl4, aggp, out, 128, 128);

    // second tuple element: the python scalar 1
    write_scalar<<<1, 1, 0, stream>>>(out + (size_t)NROWS * 256);
}

// Round 2
// 160.616 us; speedup vs baseline: 2.0759x; 2.0759x over previous
//
#include <hip/hip_runtime.h>
#include <math.h>

// ---------------------------------------------------------------------------
// Encoder_Flows on MI355X: 4x (out = agg@w_l^T + b_l + x@w_r^T; normalize); relu
// agg affects only rows [0,1024) of the flattened 32768-row x.
// agg@w_l^T == exclusive_prefix_sum(x@w_l^T)/cnt  -> tiny proj GEMM + scan.
// All GEMMs: bf16 MFMA (16x16x32), fp32 accumulate. Numeric budget: 0.02.
// ---------------------------------------------------------------------------

typedef __attribute__((ext_vector_type(8))) short short8;
typedef __attribute__((ext_vector_type(4))) float f32x4;

constexpr int NROWS = 32768;
constexpr int KROWS = 1024;

// round-to-nearest-even fp32 -> bf16
static __device__ __forceinline__ unsigned short f2bf(float f) {
    unsigned int u = __float_as_uint(f);
    unsigned int r = (u + 0x7fffu + ((u >> 16) & 1u)) >> 16;
    return (unsigned short)r;
}

// ---- convert the 8 weight matrices fp32->bf16 into one ws slab ------------
// layout: wl1[131072] wr1[131072] wl2[32768] wr2[32768] wl3[32768] wr3[32768]
//         wl4[32768] wr4[32768]   total 458752 elems
__global__ __launch_bounds__(256)
void cvt_weights(const float* __restrict__ wl1, const float* __restrict__ wr1,
                 const float* __restrict__ wl2, const float* __restrict__ wr2,
                 const float* __restrict__ wl3, const float* __restrict__ wr3,
                 const float* __restrict__ wl4, const float* __restrict__ wr4,
                 unsigned short* __restrict__ dst)
{
    int g = (blockIdx.x * 256 + threadIdx.x) * 4;
    const float* src; int off;
    if      (g < 131072) { src = wl1; off = g; }
    else if (g < 262144) { src = wr1; off = g - 131072; }
    else if (g < 294912) { src = wl2; off = g - 262144; }
    else if (g < 327680) { src = wr2; off = g - 294912; }
    else if (g < 360448) { src = wl3; off = g - 327680; }
    else if (g < 393216) { src = wr3; off = g - 360448; }
    else if (g < 425984) { src = wl4; off = g - 393216; }
    else                 { src = wr4; off = g - 425984; }
    float4 v = *reinterpret_cast<const float4*>(src + off);
    ushort4 o;
    o.x = f2bf(v.x); o.y = f2bf(v.y); o.z = f2bf(v.z); o.w = f2bf(v.w);
    *reinterpret_cast<ushort4*>(dst + g) = o;
}

// ---------------------------------------------------------------------------
// Unified MFMA GEMM.  out[i][o] = sum_k X[i][k] * W[o][k]  (+ epilogue)
//   BN = WN*64 == DOUT (one block owns full rows -> can normalize).
//   MODE 0: proj partial -> Yp slab (fp32), grid.y = k-split index
//   MODE 1: + bias + agg(rows<1024) + L2-normalize -> bf16 out
//   MODE 2: MODE1 + relu -> fp32 out (final)
// LDS tiles XOR-swizzled: byte ^= (row&7)<<4  (T2; kills ds_read_b128
// bank conflicts for 128B-stride rows).
// ---------------------------------------------------------------------------
template<int DOUT, int BM, int WM, int WN, int MODE, bool AFP32>
__global__ __launch_bounds__(256)
void mfma_gemm(const void* __restrict__ Xv,
               const unsigned short* __restrict__ W,   // (DOUT, din) bf16
               const float* __restrict__ bias,
               const float* __restrict__ aggp,         // (1024, DOUT) fp32
               float* __restrict__ outf,
               unsigned short* __restrict__ outb,
               int din, int kchunk)
{
    constexpr int BN = WN * 64;
    static_assert(BN == DOUT, "block must own full output rows");
    constexpr int FM = BM / (WM * 16);          // 16-row frags per wave (M)
    __shared__ unsigned short Abuf[BM * 64];
    __shared__ unsigned short Bbuf[BN * 64];
    __shared__ float ssred[WN * BM];

    const int t    = threadIdx.x;
    const int w    = t >> 6;
    const int lane = t & 63;
    const int wr   = w / WN;
    const int wc   = w % WN;
    const int i0   = blockIdx.x * BM;
    const int k0b  = blockIdx.y * kchunk;

    f32x4 acc[FM][4];
#pragma unroll
    for (int fi = 0; fi < FM; ++fi)
#pragma unroll
        for (int fj = 0; fj < 4; ++fj) acc[fi][fj] = (f32x4){0.f, 0.f, 0.f, 0.f};

    for (int kt = 0; kt < kchunk; kt += 64) {
        const int k0 = k0b + kt;
        if (kt) __syncthreads();
        // ---- stage A tile (BM x 64) ----
        if (AFP32) {
            const float* X = (const float*)Xv;
#pragma unroll
            for (int j = 0; j < BM / 32; ++j) {
                int idx = j * 256 + t;
                int r = idx >> 3, f = idx & 7;
                const float* src = X + (size_t)(i0 + r) * din + k0 + f * 8;
                float4 a = *reinterpret_cast<const float4*>(src);
                float4 b = *reinterpret_cast<const float4*>(src + 4);
                short8 s;
                s[0] = (short)f2bf(a.x); s[1] = (short)f2bf(a.y);
                s[2] = (short)f2bf(a.z); s[3] = (short)f2bf(a.w);
                s[4] = (short)f2bf(b.x); s[5] = (short)f2bf(b.y);
                s[6] = (short)f2bf(b.z); s[7] = (short)f2bf(b.w);
                int off = (r * 128 + f * 16) ^ ((r & 7) << 4);
                *reinterpret_cast<short8*>((char*)Abuf + off) = s;
            }
        } else {
            const unsigned short* X = (const unsigned short*)Xv;
#pragma unroll
            for (int j = 0; j < BM / 32; ++j) {
                int idx = j * 256 + t;
                int r = idx >> 3, f = idx & 7;
                short8 s = *reinterpret_cast<const short8*>(
                    X + (size_t)(i0 + r) * din + k0 + f * 8);
                int off = (r * 128 + f * 16) ^ ((r & 7) << 4);
                *reinterpret_cast<short8*>((char*)Abuf + off) = s;
            }
        }
        // ---- stage B tile (BN x 64) from bf16 weights ----
#pragma unroll
        for (int j = 0; j < BN / 32; ++j) {
            int idx = j * 256 + t;
            int r = idx >> 3, f = idx & 7;
            short8 s = *reinterpret_cast<const short8*>(
                W + (size_t)r * din + k0 + f * 8);
            int off = (r * 128 + f * 16) ^ ((r & 7) << 4);
            *reinterpret_cast<short8*>((char*)Bbuf + off) = s;
        }
        __syncthreads();
        // ---- compute: 2 x (K=32) mfma per 64-k step ----
#pragma unroll
        for (int kk = 0; kk < 2; ++kk) {
            short8 a[FM], b[4];
#pragma unroll
            for (int fi = 0; fi < FM; ++fi) {
                int rA = wr * (BM / WM) + fi * 16 + (lane & 15);
                int off = (rA * 128 + kk * 64 + (lane >> 4) * 16) ^ ((rA & 7) << 4);
                a[fi] = *reinterpret_cast<const short8*>((const char*)Abuf + off);
            }
#pragma unroll
            for (int fj = 0; fj < 4; ++fj) {
                int rB = wc * 64 + fj * 16 + (lane & 15);
                int off = (rB * 128 + kk * 64 + (lane >> 4) * 16) ^ ((rB & 7) << 4);
                b[fj] = *reinterpret_cast<const short8*>((const char*)Bbuf + off);
            }
#pragma unroll
            for (int fi = 0; fi < FM; ++fi)
#pragma unroll
                for (int fj = 0; fj < 4; ++fj)
                    acc[fi][fj] = __builtin_amdgcn_mfma_f32_16x16x32_bf16(
                        a[fi], b[fj], acc[fi][fj], 0, 0, 0);
        }
    }

    // ---- epilogue ----
    // C/D layout (m89-verified): col = lane&15, row = (lane>>4)*4 + reg
    if (MODE == 0) {
        float* dst = outf + (size_t)blockIdx.y * KROWS * DOUT;
#pragma unroll
        for (int fi = 0; fi < FM; ++fi)
#pragma unroll
            for (int fj = 0; fj < 4; ++fj)
#pragma unroll
                for (int reg = 0; reg < 4; ++reg) {
                    int rl = wr * (BM / WM) + fi * 16 + ((lane >> 4) << 2) + reg;
                    int cl = wc * 64 + fj * 16 + (lane & 15);
                    dst[(size_t)(i0 + rl) * DOUT + cl] = acc[fi][fj][reg];
                }
        return;
    }

    float bb[4];
#pragma unroll
    for (int fj = 0; fj < 4; ++fj) bb[fj] = bias[wc * 64 + fj * 16 + (lane & 15)];
    const bool hasagg = (i0 < KROWS);

#pragma unroll
    for (int fi = 0; fi < FM; ++fi)
#pragma unroll
        for (int fj = 0; fj < 4; ++fj)
#pragma unroll
            for (int reg = 0; reg < 4; ++reg) {
                int rl = wr * (BM / WM) + fi * 16 + ((lane >> 4) << 2) + reg;
                int cl = wc * 64 + fj * 16 + (lane & 15);
                float v = acc[fi][fj][reg] + bb[fj];
                if (hasagg) v += aggp[(size_t)(i0 + rl) * DOUT + cl];
                acc[fi][fj][reg] = v;
            }

    // sum of squares per row: reduce over fj (regs) then 16 col-lanes, then waves
    float sstot[FM][4];
#pragma unroll
    for (int fi = 0; fi < FM; ++fi)
#pragma unroll
        for (int reg = 0; reg < 4; ++reg) {
            float s = 0.f;
#pragma unroll
            for (int fj = 0; fj < 4; ++fj) {
                float v = acc[fi][fj][reg];
                s += v * v;
            }
#pragma unroll
            for (int m = 8; m >= 1; m >>= 1) s += __shfl_xor(s, m);
            if ((lane & 15) == 0) {
                int rl = wr * (BM / WM) + fi * 16 + ((lane >> 4) << 2) + reg;
                ssred[wc * BM + rl] = s;
            }
            sstot[fi][reg] = s;  // placeholder; replaced after barrier
        }
    __syncthreads();
#pragma unroll
    for (int fi = 0; fi < FM; ++fi)
#pragma unroll
        for (int reg = 0; reg < 4; ++reg) {
            int rl = wr * (BM / WM) + fi * 16 + ((lane >> 4) << 2) + reg;
            float s = 0.f;
#pragma unroll
            for (int c = 0; c < WN; ++c) s += ssred[c * BM + rl];
            sstot[fi][reg] = 1.0f / fmaxf(sqrtf(s), 1e-12f);
        }

#pragma unroll
    for (int fi = 0; fi < FM; ++fi)
#pragma unroll
        for (int fj = 0; fj < 4; ++fj)
#pragma unroll
            for (int reg = 0; reg < 4; ++reg) {
                int rl = wr * (BM / WM) + fi * 16 + ((lane >> 4) << 2) + reg;
                int cl = wc * 64 + fj * 16 + (lane & 15);
                float v = acc[fi][fj][reg] * sstot[fi][reg];
                if (MODE == 2) {
                    v = fmaxf(v, 0.f);
                    outf[(size_t)(i0 + rl) * DOUT + cl] = v;
                } else {
                    outb[(size_t)(i0 + rl) * DOUT + cl] = f2bf(v);
                }
            }
}

// ---- exclusive prefix-mean over 1024 rows per column (fp32, unchanged) ----
template<int DOUT>
__global__ __launch_bounds__(256)
void scan_kernel(const float* __restrict__ Ypart, float* __restrict__ aggp,
                 int nsplit)
{
    const int o = blockIdx.x;
    const int t = threadIdx.x;          // 256 threads, 4 rows each
    float v[4];
#pragma unroll
    for (int j = 0; j < 4; ++j) {
        const int i = t * 4 + j;
        float s = 0.f;
        for (int sp = 0; sp < nsplit; ++sp)
            s += Ypart[(size_t)sp * KROWS * DOUT + (size_t)i * DOUT + o];
        v[j] = s;
    }
    float tot = v[0] + v[1] + v[2] + v[3];
    const int lane = t & 63;
    const int wid  = t >> 6;
    float x = tot;
#pragma unroll
    for (int d = 1; d < 64; d <<= 1) {
        float y = __shfl_up(x, d, 64);
        if (lane >= d) x += y;
    }
    __shared__ float wsum[4];
    if (lane == 63) wsum[wid] = x;
    __syncthreads();
    float base = 0.f;
    for (int ww = 0; ww < wid; ++ww) base += wsum[ww];
    float run = base + x - tot;
#pragma unroll
    for (int j = 0; j < 4; ++j) {
        const int i = t * 4 + j;
        aggp[(size_t)i * DOUT + o] = run / fmaxf((float)i, 1.0f);
        run += v[j];
    }
}

__global__ void write_scalar(float* p) { p[0] = 1.0f; }

extern "C" void kernel_launch(void* const* d_in, const int* in_sizes, int n_in,
                              void* d_out, int out_size, void* d_ws, size_t ws_size,
                              hipStream_t stream)
{
    const float* flow = (const float*)d_in[0];
    const float* wl1 = (const float*)d_in[1];
    const float* bl1 = (const float*)d_in[2];
    const float* wr1 = (const float*)d_in[3];
    const float* wl2 = (const float*)d_in[4];
    const float* bl2 = (const float*)d_in[5];
    const float* wr2 = (const float*)d_in[6];
    const float* wl3 = (const float*)d_in[7];
    const float* bl3 = (const float*)d_in[8];
    const float* wr3 = (const float*)d_in[9];
    const float* wl4 = (const float*)d_in[10];
    const float* bl4 = (const float*)d_in[11];
    const float* wr4 = (const float*)d_in[12];
    float* out = (float*)d_out;

    char* p = (char*)d_ws;
    unsigned short* wbf = (unsigned short*)p;          p += 1 << 20;      // 458752 bf16
    unsigned short* xA  = (unsigned short*)p;          p += (size_t)NROWS * 128 * 2;
    unsigned short* xB  = (unsigned short*)p;          p += (size_t)NROWS * 256 * 2;
    float* Yp   = (float*)p;                           p += (size_t)4 * KROWS * 256 * 4;
    float* aggp = (float*)p;

    const unsigned short* wl1b = wbf;
    const unsigned short* wr1b = wbf + 131072;
    const unsigned short* wl2b = wbf + 262144;
    const unsigned short* wr2b = wbf + 294912;
    const unsigned short* wl3b = wbf + 327680;
    const unsigned short* wr3b = wbf + 360448;
    const unsigned short* wl4b = wbf + 393216;
    const unsigned short* wr4b = wbf + 425984;

    cvt_weights<<<448, 256, 0, stream>>>(wl1, wr1, wl2, wr2, wl3, wr3, wl4, wr4, wbf);

    // ---- Layer 1: din=1024, dout=128, X=flow (fp32) ----
    mfma_gemm<128, 64, 2, 2, 0, true ><<<dim3(16, 4), 256, 0, stream>>>(
        flow, wl1b, nullptr, nullptr, Yp, nullptr, 1024, 256);
    scan_kernel<128><<<128, 256, 0, stream>>>(Yp, aggp, 4);
    mfma_gemm<128, 64, 2, 2, 1, true ><<<dim3(512, 1), 256, 0, stream>>>(
        flow, wr1b, bl1, aggp, nullptr, xA, 1024, 1024);

    // ---- Layer 2: din=128, dout=256 ----
    mfma_gemm<256, 64, 1, 4, 0, false><<<dim3(16, 2), 256, 0, stream>>>(
        xA, wl2b, nullptr, nullptr, Yp, nullptr, 128, 64);
    scan_kernel<256><<<256, 256, 0, stream>>>(Yp, aggp, 2);
    mfma_gemm<256, 64, 1, 4, 1, false><<<dim3(512, 1), 256, 0, stream>>>(
        xA, wr2b, bl2, aggp, nullptr, xB, 128, 128);

    // ---- Layer 3: din=256, dout=128 ----
    mfma_gemm<128, 64, 2, 2, 0, false><<<dim3(16, 4), 256, 0, stream>>>(
        xB, wl3b, nullptr, nullptr, Yp, nullptr, 256, 64);
    scan_kernel<128><<<128, 256, 0, stream>>>(Yp, aggp, 4);
    mfma_gemm<128, 64, 2, 2, 1, false><<<dim3(512, 1), 256, 0, stream>>>(
        xB, wr3b, bl3, aggp, nullptr, xA, 256, 256);

    // ---- Layer 4: din=128, dout=256, + ReLU -> fp32 out ----
    mfma_gemm<256, 64, 1, 4, 0, false><<<dim3(16, 2), 256, 0, stream>>>(
        xA, wl4b, nullptr, nullptr, Yp, nullptr, 128, 64);
    scan_kernel<256><<<256, 256, 0, stream>>>(Yp, aggp, 2);
    mfma_gemm<256, 64, 1, 4, 2, false><<<dim3(512, 1), 256, 0, stream>>>(
        xA, wr4b, bl4, aggp, out, nullptr, 128, 128);

    write_scalar<<<1, 1, 0, stream>>>(out + (size_t)NROWS * 256);
}